// Round 15
// baseline (171.621 us; speedup 1.0000x reference)
//
#include <hip/hip_runtime.h>
#include <hip/hip_bf16.h>

// NT-Xent, BATCH=4096, N=8192, D=512, TEMP=0.1 — bf16 MFMA.
// Round 15: BARRIER-FREE 1-wave blocks. 64 threads/block, per-wave 64x64
// (4x4 of 16x16), BK=32, private 16 KB LDS dbuf -> 10 blocks/CU, zero
// s_barrier (staging wave == consuming wave; vmcnt + in-order issue + lgkm
// discipline give all the ordering). Kills the barrier convoy that kept
// every multi-wave variant at >2x above the busiest pipe.
// loss = mean_i [ logsumexp_{j!=i} sim[i,j] - sim[i,partner(i)] ]
// acc  = mean_i [ sim[i,partner(i)] >= max_{j!=i,partner} sim[i,j] ]
// sim = (msg_n . img_n^T)/TEMP, 10x folded into msg side before bf16 cast.

#define NROWS 8192
#define BATCHD 4096
#define DIM 512
#define BT 64              // block tile (rows and cols)
#define BK 32
#define NSTEP (DIM / BK)   // 16 K-steps
#define SHIFT 10.0f

typedef short bf16x8 __attribute__((ext_vector_type(8)));
typedef float f32x4 __attribute__((ext_vector_type(4)));

#define GLDS(g, l)                                                             \
    __builtin_amdgcn_global_load_lds(                                          \
        (const __attribute__((address_space(1))) void*)(g),                    \
        (__attribute__((address_space(3))) void*)(l), 16, 0, 0)

__device__ __forceinline__ unsigned f2u_ord(float f) {
    unsigned u = __float_as_uint(f);
    return (u & 0x80000000u) ? ~u : (u | 0x80000000u);
}
__device__ __forceinline__ float u2f_ord(unsigned e) {
    return (e & 0x80000000u) ? __uint_as_float(e & 0x7fffffffu) : __uint_as_float(~e);
}
__device__ __forceinline__ short f2bf(float f) {  // RNE f32 -> bf16 bits
    unsigned u = __float_as_uint(f);
    return (short)((u + 0x7fffu + ((u >> 16) & 1u)) >> 16);
}

// blocks 0..NROWS-1: msg (x10); NROWS..2*NROWS-1: img (x1).
// First 128 blocks also zero rowsum/rowmax/accum.
__global__ __launch_bounds__(64) void normalize_bf16_both(const float* __restrict__ msg,
                                                          const float* __restrict__ img,
                                                          short* __restrict__ mnb,
                                                          short* __restrict__ imb,
                                                          float* __restrict__ rowsum,
                                                          unsigned* __restrict__ rowmax,
                                                          float* __restrict__ accum) {
    if (blockIdx.x < 128) {
        const int i = blockIdx.x * 64 + threadIdx.x;
        rowsum[i] = 0.f;
        rowmax[i] = 0u;  // encodes "most negative"
        if (i < 2) accum[i] = 0.f;
    }
    int row = blockIdx.x;
    const float* in;
    short* out;
    float scale;
    if (row < NROWS) { in = msg; out = mnb; scale = 10.0f; }
    else { row -= NROWS; in = img; out = imb; scale = 1.0f; }
    const int lane = threadIdx.x;
    const float* src = in + (size_t)row * DIM + lane * 8;
    float4 v0 = *(const float4*)(src);
    float4 v1 = *(const float4*)(src + 4);
    float ss = v0.x*v0.x + v0.y*v0.y + v0.z*v0.z + v0.w*v0.w
             + v1.x*v1.x + v1.y*v1.y + v1.z*v1.z + v1.w*v1.w;
    #pragma unroll
    for (int off = 1; off < 64; off <<= 1) ss += __shfl_xor(ss, off);
    const float inv = scale / fmaxf(sqrtf(ss), 1e-8f);
    float vv[8] = {v0.x, v0.y, v0.z, v0.w, v1.x, v1.y, v1.z, v1.w};
    bf16x8 o;
    #pragma unroll
    for (int j = 0; j < 8; ++j) o[j] = f2bf(vv[j] * inv);
    *(bf16x8*)(out + (size_t)row * DIM + lane * 8) = o;
}

// A = msg_n*10 (bf16), B = img_n (bf16); row-major [8192][512].
// 1-wave block, 64x64 tile, BK=32, no barriers.
// LDS per buffer per matrix: [64 rows][4 chunks of 16B]; chunk-slot p of
// row r holds logical chunk p ^ ((r>>1)&3) (verified 0-conflict pattern);
// linear GLDS dest, pre-swizzled global source.
__global__ __launch_bounds__(64, 3) void simloss_mfma(const short* __restrict__ A,
                                                      const short* __restrict__ B,
                                                      float* __restrict__ rowsum,
                                                      unsigned* __restrict__ rowmax,
                                                      float* __restrict__ rowpos) {
    __shared__ __attribute__((aligned(16))) short As[2][BT * BK];  // 2 x 4 KB
    __shared__ __attribute__((aligned(16))) short Bs[2][BT * BK];  // 2 x 4 KB

    const int tid = threadIdx.x;     // == lane
    const int g = tid >> 4;          // k-chunk 0..3
    const int r16 = tid & 15;

    // XCD stripes, bx-major traversal (by fastest): 16384 blocks =
    // 128 by x 128 bx; XCD k owns by in [k*16, k*16+16). Co-resident blocks
    // (consecutive bids) share bx -> same B panel -> L1/L2-hot B.
    const int bid = blockIdx.x;
    const int xcd = bid & 7;
    const int l = bid >> 3;          // 0..2047
    const int by = xcd * 16 + (l & 15);
    const int bx = l >> 4;           // 0..127
    const int rowBase = by * BT;
    const int colBase = bx * BT;

    // staging: slot s = i*64 + tid (i=0..3), row = s>>2, slot-chunk = s&3;
    // fetch logical chunk (s&3)^((row>>1)&3). With i*64 ≡ 0 (mod 4) and
    // i*16 even, the lane's chunk is independent of i:
    const int srow = tid >> 2;                       // 0..15 (+ i*16)
    const int sc = (tid & 3) ^ ((srow >> 1) & 3);
    const short* gA = A + (size_t)(rowBase + srow) * DIM + sc * 8;
    const short* gB = B + (size_t)(colBase + srow) * DIM + sc * 8;

#define STAGE(b, koff)                                                  \
    do {                                                                \
        _Pragma("unroll") for (int i = 0; i < 4; ++i) {                 \
            GLDS(gA + (size_t)i * 16 * DIM + (koff), &As[b][i * 512 + tid * 8]); \
            GLDS(gB + (size_t)i * 16 * DIM + (koff), &Bs[b][i * 512 + tid * 8]); \
        }                                                               \
    } while (0)

    // fragment read bases (shorts); same XOR on read side (verified shape)
    const int swz = (r16 >> 1) & 3;
    const int aBase = r16 * BK + ((g ^ swz) * 8);

    f32x4 acc[4][4] = {};

#define VMCNT(n) asm volatile("s_waitcnt vmcnt(" #n ")" ::: "memory")

    // prologue: stage tile 0 (8 GLDS in flight)
    STAGE(0, 0);

    for (int t = 0; t < NSTEP; ++t) {
        const int b = t & 1;
        if (t < NSTEP - 1) {
            STAGE(b ^ 1, (t + 1) * BK);  // 8 GLDS for t+1 in flight
            VMCNT(8);                    // tile t's 8 landed (issued 1 step ago)
        } else {
            VMCNT(0);
        }
        // no barrier: this wave staged it, this wave reads it.
        bf16x8 af[4], bfr[4];
        #pragma unroll
        for (int m = 0; m < 4; ++m)
            af[m] = *(const bf16x8*)&As[b][aBase + m * 16 * BK];
        #pragma unroll
        for (int n = 0; n < 4; ++n)
            bfr[n] = *(const bf16x8*)&Bs[b][aBase + n * 16 * BK];
        __builtin_amdgcn_s_setprio(1);
        #pragma unroll
        for (int m = 0; m < 4; ++m)
            #pragma unroll
            for (int n = 0; n < 4; ++n)
                acc[m][n] = __builtin_amdgcn_mfma_f32_16x16x32_bf16(
                    af[m], bfr[n], acc[m][n], 0, 0, 0);
        __builtin_amdgcn_s_setprio(0);
        // WAR safety for next STAGE into buf b^1: its last ds_reads (step t-1)
        // completed before step t-1's MFMAs issued (compiler lgkm waits), and
        // issue is in-order — so the slots are free. No sync needed.
    }

    // ---- fused epilogue (no LDS, no barriers) ----
    // C/D layout: col = lane&15 (r16), row = g*4 + reg  [m89 verified]
    const int baseRow = rowBase + g * 4;
    const int baseCol = colBase + r16;
    #pragma unroll
    for (int m = 0; m < 4; ++m) {
        #pragma unroll
        for (int reg = 0; reg < 4; ++reg) {
            const int i = baseRow + m * 16 + reg;
            const int partner = i ^ BATCHD;
            float sum = 0.f, mx = -1e30f;
            #pragma unroll
            for (int n = 0; n < 4; ++n) {
                const int j = baseCol + n * 16;
                const float s = acc[m][n][reg];
                const bool isDiag = (j == i);
                const bool isPos = (j == partner);
                float e = __expf(s - SHIFT);
                if (isDiag) e = 0.f;
                sum += e;
                if (!isDiag && !isPos) mx = fmaxf(mx, s);
                if (isPos) rowpos[i] = s;  // exactly one writer grid-wide
            }
            #pragma unroll
            for (int off = 1; off < 16; off <<= 1) {
                sum += __shfl_xor(sum, off);
                mx = fmaxf(mx, __shfl_xor(mx, off));
            }
            if (r16 == 0) {
                atomicAdd(&rowsum[i], sum);
                atomicMax(&rowmax[i], f2u_ord(mx));
            }
        }
    }
#undef STAGE
#undef VMCNT
}

// 32 blocks x 256 threads: one row per thread, block-reduce, atomic combine.
__global__ __launch_bounds__(256) void finalize_partial(const float* __restrict__ rowsum,
                                                        const unsigned* __restrict__ rowmax,
                                                        const float* __restrict__ rowpos,
                                                        float* __restrict__ accum) {
    const int tid = threadIdx.x;
    const int i = blockIdx.x * 256 + tid;
    const float lse = SHIFT + logf(rowsum[i]);
    const float pos = rowpos[i];
    float lossAcc = lse - pos;
    float hitAcc = (pos >= u2f_ord(rowmax[i])) ? 1.f : 0.f;
    __shared__ float sl[256], sa[256];
    sl[tid] = lossAcc; sa[tid] = hitAcc;
    __syncthreads();
    for (int s = 128; s > 0; s >>= 1) {
        if (tid < s) { sl[tid] += sl[tid + s]; sa[tid] += sa[tid + s]; }
        __syncthreads();
    }
    if (tid == 0) {
        atomicAdd(&accum[0], sl[0]);
        atomicAdd(&accum[1], sa[0]);
    }
}

__global__ void finalize_write(const float* __restrict__ accum, float* __restrict__ out) {
    if (threadIdx.x == 0) {
        out[0] = accum[0] / (float)NROWS;
        out[1] = accum[1] / (float)NROWS;
    }
}

extern "C" void kernel_launch(void* const* d_in, const int* in_sizes, int n_in,
                              void* d_out, int out_size, void* d_ws, size_t ws_size,
                              hipStream_t stream) {
    const float* msg = (const float*)d_in[0];
    const float* img = (const float*)d_in[1];
    float* out = (float*)d_out;

    char* ws = (char*)d_ws;
    const size_t matBytes = (size_t)NROWS * DIM * sizeof(short);  // 8 MB
    short* mnb = (short*)ws;
    short* imb = (short*)(ws + matBytes);
    float* rowsum = (float*)(ws + 2 * matBytes);
    unsigned* rowmax = (unsigned*)(ws + 2 * matBytes + NROWS * sizeof(float));
    float* rowpos = (float*)(ws + 2 * matBytes + 2 * NROWS * sizeof(float));
    float* accum = (float*)(ws + 2 * matBytes + 3 * NROWS * sizeof(float));

    normalize_bf16_both<<<2 * NROWS, 64, 0, stream>>>(msg, img, mnb, imb,
                                                      rowsum, rowmax, accum);

    simloss_mfma<<<(NROWS / BT) * (NROWS / BT), 64, 0, stream>>>(mnb, imb, rowsum,
                                                                 rowmax, rowpos);

    finalize_partial<<<NROWS / 256, 256, 0, stream>>>(rowsum, rowmax, rowpos, accum);
    finalize_write<<<1, 64, 0, stream>>>(accum, out);
}